// Round 2
// baseline (1853.881 us; speedup 1.0000x reference)
//
#include <hip/hip_runtime.h>

#define NN 100000
#define NE 1000000
#define D 128
#define ALPHA 0.5f

// ---------------------------------------------------------------------------
// K0: build fused weight W2[k][j] (128 x 256):
//   j <  128: ALPHA     * W_sd[j][k]
//   j >= 128: (1-ALPHA) * W_ds[j-128][k]
// So y = x @ W2 gives y[n] = [ALPHA*x@Wsd^T | (1-ALPHA)*x@Wds^T].
// ---------------------------------------------------------------------------
__global__ __launch_bounds__(256) void build_w2(const float* __restrict__ Wsd,
                                                const float* __restrict__ Wds,
                                                float* __restrict__ W2) {
    int idx = blockIdx.x * 256 + threadIdx.x;   // 0..32767, idx = k*256 + j
    int k = idx >> 8;
    int j = idx & 255;
    float v;
    if (j < 128) v = ALPHA * Wsd[j * D + k];
    else         v = (1.0f - ALPHA) * Wds[(j - 128) * D + k];
    W2[idx] = v;
}

// ---------------------------------------------------------------------------
// K1: out[n][d] = ALPHA*b_sd[d] + (1-ALPHA)*b_ds[d]   (bias init, full write;
// required every call since harness re-poisons d_out with 0xAA)
// ---------------------------------------------------------------------------
__global__ __launch_bounds__(256) void init_out(const float* __restrict__ bsd,
                                                const float* __restrict__ bds,
                                                float* __restrict__ out) {
    int idx = blockIdx.x * 256 + threadIdx.x;   // float4 index over NN*D/4
    int d4 = (idx & 31) << 2;
    float4 v;
    v.x = ALPHA * bsd[d4 + 0] + (1.0f - ALPHA) * bds[d4 + 0];
    v.y = ALPHA * bsd[d4 + 1] + (1.0f - ALPHA) * bds[d4 + 1];
    v.z = ALPHA * bsd[d4 + 2] + (1.0f - ALPHA) * bds[d4 + 2];
    v.w = ALPHA * bsd[d4 + 3] + (1.0f - ALPHA) * bds[d4 + 3];
    ((float4*)out)[idx] = v;
}

// ---------------------------------------------------------------------------
// K2: transform GEMM  y[M][256] = x[M][128] @ W2[128][256]
// 64x64 tile / 256-thread block, 4x4 per thread, f32 vector FMA.
// A-tile in LDS (natural [row][k] layout, pad 132 -> staged writes coalesced,
// k-loop reads 2-way bank alias = free). B read direct from global: W2 is
// 128 KB, L2-resident; saves 32 KB LDS (total LDS 33.8 KB <= 64 KB limit,
// 4 blocks/CU).
// ---------------------------------------------------------------------------
__global__ __launch_bounds__(256) void transform(const float* __restrict__ x,
                                                 const float* __restrict__ W2,
                                                 float* __restrict__ y) {
    __shared__ float As[64][132];   // 33792 B
    const int tid  = threadIdx.x;
    const int brow = blockIdx.x * 64;
    const int bcol = blockIdx.y * 64;

    // Stage A tile: x[brow+r][0:128] -> As[r][0:128], coalesced float4 copies.
#pragma unroll
    for (int i = 0; i < 8; ++i) {
        int f   = tid + i * 256;        // float4 index 0..2047
        int row = f >> 5;               // 0..63
        int kc  = (f & 31) << 2;        // 0,4,...,124
        float4 g = make_float4(0.f, 0.f, 0.f, 0.f);
        int grow = brow + row;
        if (grow < NN) g = *(const float4*)&x[(size_t)grow * D + kc];
        *(float4*)&As[row][kc] = g;
    }
    __syncthreads();

    const int ty = tid >> 4;            // 0..15 -> output rows ty*4..ty*4+3
    const int tx = tid & 15;            // 0..15 -> output cols tx*4..tx*4+3
    float acc[4][4];
#pragma unroll
    for (int i = 0; i < 4; ++i)
#pragma unroll
        for (int j = 0; j < 4; ++j) acc[i][j] = 0.f;

#pragma unroll 2
    for (int k0 = 0; k0 < 128; k0 += 4) {
        float av[4][4], bv[4][4];
#pragma unroll
        for (int i = 0; i < 4; ++i) {
            float4 t = *(const float4*)&As[ty * 4 + i][k0];
            av[i][0] = t.x; av[i][1] = t.y; av[i][2] = t.z; av[i][3] = t.w;
        }
#pragma unroll
        for (int j = 0; j < 4; ++j) {
            float4 t = *(const float4*)&W2[(size_t)(k0 + j) * 256 + bcol + tx * 4];
            bv[j][0] = t.x; bv[j][1] = t.y; bv[j][2] = t.z; bv[j][3] = t.w;
        }
#pragma unroll
        for (int i = 0; i < 4; ++i)
#pragma unroll
            for (int c = 0; c < 4; ++c)
#pragma unroll
                for (int kk = 0; kk < 4; ++kk)
                    acc[i][c] += av[i][kk] * bv[kk][c];
    }

#pragma unroll
    for (int i = 0; i < 4; ++i) {
        int row = brow + ty * 4 + i;
        if (row < NN) {
            float4 v = make_float4(acc[i][0], acc[i][1], acc[i][2], acc[i][3]);
            *(float4*)&y[(size_t)row * 256 + bcol + tx * 4] = v;
        }
    }
}

// ---------------------------------------------------------------------------
// K3: scatter. One wave per edge; lane handles 2 floats of each direction.
//   out[dst] += y[src][0:128]      (ALPHA * x@Wsd^T, pre-scaled)
//   out[src] += y[dst][128:256]    ((1-ALPHA) * x@Wds^T, pre-scaled)
// unsafeAtomicAdd forces HW global_atomic_add_f32 (plain atomicAdd(float*)
// may lower to a CAS loop without -munsafe-fp-atomics).
// ---------------------------------------------------------------------------
__global__ __launch_bounds__(256) void scatter(const int* __restrict__ esrc,
                                               const int* __restrict__ edst,
                                               const float* __restrict__ y,
                                               float* __restrict__ out) {
    const int lane = threadIdx.x & 63;
    const int wave = blockIdx.x * 4 + (threadIdx.x >> 6);
    const int nw   = gridDim.x * 4;
    const int l2   = lane << 1;
    for (int e = wave; e < NE; e += nw) {
        int s = esrc[e];
        int d = edst[e];
        float2 a = *(const float2*)&y[(size_t)s * 256 + l2];
        float2 b = *(const float2*)&y[(size_t)d * 256 + 128 + l2];
        float* od = &out[(size_t)d * D + l2];
        float* os = &out[(size_t)s * D + l2];
        unsafeAtomicAdd(od + 0, a.x);
        unsafeAtomicAdd(od + 1, a.y);
        unsafeAtomicAdd(os + 0, b.x);
        unsafeAtomicAdd(os + 1, b.y);
    }
}

// ---------------------------------------------------------------------------
extern "C" void kernel_launch(void* const* d_in, const int* in_sizes, int n_in,
                              void* d_out, int out_size, void* d_ws, size_t ws_size,
                              hipStream_t stream) {
    const float* x    = (const float*)d_in[0];
    const int*   esrc = (const int*)  d_in[1];
    const int*   edst = (const int*)  d_in[2];
    const float* Wsd  = (const float*)d_in[3];
    const float* bsd  = (const float*)d_in[4];
    const float* Wds  = (const float*)d_in[5];
    const float* bds  = (const float*)d_in[6];
    float* out = (float*)d_out;

    float* y  = (float*)d_ws;                                   // NN*256 f32 = 102.4 MB
    float* W2 = (float*)((char*)d_ws + (size_t)NN * 256 * 4);   // 128*256 f32

    build_w2<<<128, 256, 0, stream>>>(Wsd, Wds, W2);
    init_out<<<(NN * D / 4) / 256, 256, 0, stream>>>(bsd, bds, out);
    transform<<<dim3((NN + 63) / 64, 4), 256, 0, stream>>>(x, W2, y);
    scatter<<<2048, 256, 0, stream>>>(esrc, edst, y, out);
}

// Round 5
// 614.438 us; speedup vs baseline: 3.0172x; 3.0172x over previous
//
#include <hip/hip_runtime.h>

#define NN 100000
#define NE 1000000
#define D 128
#define ALPHA 0.5f

// ---------------- workspace layout (bytes) ----------------
// y      [NN][256] f32 : 0           .. 102,400,000
// W2     [128][256] f32: 102,400,000 .. +131,072
// cnt    [NN] i32      : 102,531,072 .. +400,000
// start  [NN] i32      : 102,931,072 .. +400,000
// cur    [NN] i32      : 103,331,072 .. +400,000
// cursor i32 (pad 256) : 103,731,072
// buf    [2*NE] i32    : 103,731,328 .. +8,000,000  => need 111,731,328 B
#define OFF_W2     102400000UL
#define OFF_CNT    102531072UL
#define OFF_START  102931072UL
#define OFF_CUR    103331072UL
#define OFF_CURSOR 103731072UL
#define OFF_BUF    103731328UL
#define WS_NEEDED  (OFF_BUF + (size_t)2 * NE * 4)

// ---------------------------------------------------------------------------
// K0: fused weight W2[k][j] (128 x 256):
//   j<128: ALPHA*W_sd[j][k];  j>=128: (1-ALPHA)*W_ds[j-128][k]
// y = x @ W2  ->  y[n] = [ALPHA*x@Wsd^T | (1-ALPHA)*x@Wds^T]
// ---------------------------------------------------------------------------
__global__ __launch_bounds__(256) void build_w2(const float* __restrict__ Wsd,
                                                const float* __restrict__ Wds,
                                                float* __restrict__ W2) {
    int idx = blockIdx.x * 256 + threadIdx.x;
    int k = idx >> 8;
    int j = idx & 255;
    float v;
    if (j < 128) v = ALPHA * Wsd[j * D + k];
    else         v = (1.0f - ALPHA) * Wds[(j - 128) * D + k];
    W2[idx] = v;
}

// ---------------------------------------------------------------------------
// K2: transform GEMM  y[M][256] = x[M][128] @ W2[128][256]
// 64x64 tile / 256-thread block, 4x4 per thread, f32 vector FMA.
// A-tile in LDS; B (128 KB) direct from global, L2-resident.
// ---------------------------------------------------------------------------
__global__ __launch_bounds__(256) void transform(const float* __restrict__ x,
                                                 const float* __restrict__ W2,
                                                 float* __restrict__ y) {
    __shared__ float As[64][132];   // 33792 B
    const int tid  = threadIdx.x;
    const int brow = blockIdx.x * 64;
    const int bcol = blockIdx.y * 64;

#pragma unroll
    for (int i = 0; i < 8; ++i) {
        int f   = tid + i * 256;
        int row = f >> 5;
        int kc  = (f & 31) << 2;
        float4 g = make_float4(0.f, 0.f, 0.f, 0.f);
        int grow = brow + row;
        if (grow < NN) g = *(const float4*)&x[(size_t)grow * D + kc];
        *(float4*)&As[row][kc] = g;
    }
    __syncthreads();

    const int ty = tid >> 4;
    const int tx = tid & 15;
    float acc[4][4];
#pragma unroll
    for (int i = 0; i < 4; ++i)
#pragma unroll
        for (int j = 0; j < 4; ++j) acc[i][j] = 0.f;

#pragma unroll 2
    for (int k0 = 0; k0 < 128; k0 += 4) {
        float av[4][4], bv[4][4];
#pragma unroll
        for (int i = 0; i < 4; ++i) {
            float4 t = *(const float4*)&As[ty * 4 + i][k0];
            av[i][0] = t.x; av[i][1] = t.y; av[i][2] = t.z; av[i][3] = t.w;
        }
#pragma unroll
        for (int j = 0; j < 4; ++j) {
            float4 t = *(const float4*)&W2[(size_t)(k0 + j) * 256 + bcol + tx * 4];
            bv[j][0] = t.x; bv[j][1] = t.y; bv[j][2] = t.z; bv[j][3] = t.w;
        }
#pragma unroll
        for (int i = 0; i < 4; ++i)
#pragma unroll
            for (int c = 0; c < 4; ++c)
#pragma unroll
                for (int kk = 0; kk < 4; ++kk)
                    acc[i][c] += av[i][kk] * bv[kk][c];
    }

#pragma unroll
    for (int i = 0; i < 4; ++i) {
        int row = brow + ty * 4 + i;
        if (row < NN) {
            float4 v = make_float4(acc[i][0], acc[i][1], acc[i][2], acc[i][3]);
            *(float4*)&y[(size_t)row * 256 + bcol + tx * 4] = v;
        }
    }
}

// ---------------------------------------------------------------------------
// CSR build: bucket of node n holds y-row float-offsets:
//   edge (s,d):  bucket[d] += {s*256}        (gather yA half of src)
//                bucket[s] += {d*256 + 128}  (gather yB half of dst)
// Max value 100000*256+128 < 2^31. Bucket order arbitrary (atomic fill).
// ---------------------------------------------------------------------------
__global__ __launch_bounds__(256) void zero_cnt(int* __restrict__ cnt,
                                                int* __restrict__ cursor) {
    int i = blockIdx.x * 256 + threadIdx.x;
    if (i < NN) cnt[i] = 0;
    if (i == 0) *cursor = 0;
}

__global__ __launch_bounds__(256) void hist(const int* __restrict__ esrc,
                                            const int* __restrict__ edst,
                                            int* __restrict__ cnt) {
    int e = blockIdx.x * 256 + threadIdx.x;
    if (e < NE) {
        atomicAdd(&cnt[edst[e]], 1);
        atomicAdd(&cnt[esrc[e]], 1);
    }
}

// Disjoint range allocation: wave-level inclusive scan + one atomic per wave.
__global__ __launch_bounds__(256) void alloc_ranges(const int* __restrict__ cnt,
                                                    int* __restrict__ start,
                                                    int* __restrict__ cur,
                                                    int* __restrict__ cursor) {
    int n    = blockIdx.x * 256 + threadIdx.x;
    int lane = threadIdx.x & 63;
    int v    = (n < NN) ? cnt[n] : 0;
    int incl = v;
#pragma unroll
    for (int off = 1; off < 64; off <<= 1) {
        int t = __shfl_up(incl, off, 64);
        if (lane >= off) incl += t;
    }
    int total = __shfl(incl, 63, 64);
    int base  = 0;
    if (lane == 63) base = atomicAdd(cursor, total);
    base = __shfl(base, 63, 64);
    if (n < NN) {
        int s = base + incl - v;   // exclusive prefix within wave
        start[n] = s;
        cur[n]   = s;
    }
}

__global__ __launch_bounds__(256) void fill(const int* __restrict__ esrc,
                                            const int* __restrict__ edst,
                                            int* __restrict__ cur,
                                            int* __restrict__ buf) {
    int e = blockIdx.x * 256 + threadIdx.x;
    if (e < NE) {
        int s = esrc[e], d = edst[e];
        int p = atomicAdd(&cur[d], 1);
        buf[p] = s * 256;                // yA half of src
        int q = atomicAdd(&cur[s], 1);
        buf[q] = d * 256 + 128;          // yB half of dst
    }
}

// ---------------------------------------------------------------------------
// K3: gather. One wave per node; lane handles dims {2l, 2l+1}.
// out[n] = blended bias + sum over bucket of y[offset + lane*2 .. +1].
// Zero fp atomics; single streaming write per out row. 4-deep load unroll
// to keep >=4 scattered L2/L3 reads in flight per wave.
// ---------------------------------------------------------------------------
__global__ __launch_bounds__(256) void gather(const int* __restrict__ start,
                                              const int* __restrict__ cnt,
                                              const int* __restrict__ buf,
                                              const float* __restrict__ y,
                                              const float* __restrict__ bsd,
                                              const float* __restrict__ bds,
                                              float* __restrict__ out) {
    int wave = blockIdx.x * 4 + (threadIdx.x >> 6);
    int lane = threadIdx.x & 63;
    if (wave >= NN) return;
    const int n  = wave;
    const int s0 = start[n];
    const int e0 = s0 + cnt[n];
    const int l2 = lane << 1;

    float a0 = ALPHA * bsd[l2]     + (1.0f - ALPHA) * bds[l2];
    float a1 = ALPHA * bsd[l2 + 1] + (1.0f - ALPHA) * bds[l2 + 1];

    int i = s0;
    for (; i + 4 <= e0; i += 4) {
        int v0 = buf[i], v1 = buf[i + 1], v2 = buf[i + 2], v3 = buf[i + 3];
        float2 p0 = *(const float2*)&y[(size_t)v0 + l2];
        float2 p1 = *(const float2*)&y[(size_t)v1 + l2];
        float2 p2 = *(const float2*)&y[(size_t)v2 + l2];
        float2 p3 = *(const float2*)&y[(size_t)v3 + l2];
        a0 += p0.x + p1.x + p2.x + p3.x;
        a1 += p0.y + p1.y + p2.y + p3.y;
    }
    for (; i < e0; ++i) {
        int v0 = buf[i];
        float2 p0 = *(const float2*)&y[(size_t)v0 + l2];
        a0 += p0.x;
        a1 += p0.y;
    }
    *(float2*)&out[(size_t)n * D + l2] = make_float2(a0, a1);
}

// ---------------------------------------------------------------------------
// Fallback path (used only if ws_size < WS_NEEDED): verified round-2 kernels.
// ---------------------------------------------------------------------------
__global__ __launch_bounds__(256) void init_out(const float* __restrict__ bsd,
                                                const float* __restrict__ bds,
                                                float* __restrict__ out) {
    int idx = blockIdx.x * 256 + threadIdx.x;
    int d4 = (idx & 31) << 2;
    float4 v;
    v.x = ALPHA * bsd[d4 + 0] + (1.0f - ALPHA) * bds[d4 + 0];
    v.y = ALPHA * bsd[d4 + 1] + (1.0f - ALPHA) * bds[d4 + 1];
    v.z = ALPHA * bsd[d4 + 2] + (1.0f - ALPHA) * bds[d4 + 2];
    v.w = ALPHA * bsd[d4 + 3] + (1.0f - ALPHA) * bds[d4 + 3];
    ((float4*)out)[idx] = v;
}

__global__ __launch_bounds__(256) void scatter(const int* __restrict__ esrc,
                                               const int* __restrict__ edst,
                                               const float* __restrict__ y,
                                               float* __restrict__ out) {
    const int lane = threadIdx.x & 63;
    const int wave = blockIdx.x * 4 + (threadIdx.x >> 6);
    const int nw   = gridDim.x * 4;
    const int l2   = lane << 1;
    for (int e = wave; e < NE; e += nw) {
        int s = esrc[e];
        int d = edst[e];
        float2 a = *(const float2*)&y[(size_t)s * 256 + l2];
        float2 b = *(const float2*)&y[(size_t)d * 256 + 128 + l2];
        float* od = &out[(size_t)d * D + l2];
        float* os = &out[(size_t)s * D + l2];
        unsafeAtomicAdd(od + 0, a.x);
        unsafeAtomicAdd(od + 1, a.y);
        unsafeAtomicAdd(os + 0, b.x);
        unsafeAtomicAdd(os + 1, b.y);
    }
}

// ---------------------------------------------------------------------------
extern "C" void kernel_launch(void* const* d_in, const int* in_sizes, int n_in,
                              void* d_out, int out_size, void* d_ws, size_t ws_size,
                              hipStream_t stream) {
    const float* x    = (const float*)d_in[0];
    const int*   esrc = (const int*)  d_in[1];
    const int*   edst = (const int*)  d_in[2];
    const float* Wsd  = (const float*)d_in[3];
    const float* bsd  = (const float*)d_in[4];
    const float* Wds  = (const float*)d_in[5];
    const float* bds  = (const float*)d_in[6];
    float* out = (float*)d_out;

    char* ws = (char*)d_ws;
    float* y  = (float*)ws;
    float* W2 = (float*)(ws + OFF_W2);

    build_w2<<<128, 256, 0, stream>>>(Wsd, Wds, W2);
    transform<<<dim3((NN + 63) / 64, 4), 256, 0, stream>>>(x, W2, y);

    if (ws_size >= WS_NEEDED) {
        int* cnt    = (int*)(ws + OFF_CNT);
        int* start  = (int*)(ws + OFF_START);
        int* cur    = (int*)(ws + OFF_CUR);
        int* cursor = (int*)(ws + OFF_CURSOR);
        int* buf    = (int*)(ws + OFF_BUF);
        zero_cnt<<<(NN + 255) / 256, 256, 0, stream>>>(cnt, cursor);
        hist<<<(NE + 255) / 256, 256, 0, stream>>>(esrc, edst, cnt);
        alloc_ranges<<<(NN + 255) / 256, 256, 0, stream>>>(cnt, start, cur, cursor);
        fill<<<(NE + 255) / 256, 256, 0, stream>>>(esrc, edst, cur, buf);
        gather<<<(NN + 3) / 4, 256, 0, stream>>>(start, cnt, buf, y, bsd, bds, out);
    } else {
        init_out<<<(NN * D / 4) / 256, 256, 0, stream>>>(bsd, bds, out);
        scatter<<<2048, 256, 0, stream>>>(esrc, edst, y, out);
    }
}

// Round 9
// 419.107 us; speedup vs baseline: 4.4234x; 1.4661x over previous
//
#include <hip/hip_runtime.h>

#define NN 100000
#define NE 1000000
#define D 128
#define ALPHA 0.5f

// ---------------- workspace layout (bytes) ----------------
// y      [NN][256] f32 : 0           .. 102,400,000
// W2     [128][256] f32: 102,400,000 .. +131,072
// cnt    [NN] i32      : 102,531,072 .. +400,000   (cnt_out; also old-path cnt)
// start  [NN] i32      : 102,931,072 .. +400,000
// cur    [NN] i32      : 103,331,072 .. +400,000   (old path; new path: bin arrays)
// cursor i32           : 103,731,072               (old path)
// buf    [2*NE] i32    : 103,731,328 .. +8,000,000 => old need 111,731,328
// rec4   [2*NE] i32    : 111,731,328 .. +8,000,000 => new need 119,731,328
#define OFF_W2     102400000UL
#define OFF_CNT    102531072UL
#define OFF_START  102931072UL
#define OFF_CUR    103331072UL
#define OFF_CURSOR 103731072UL
#define OFF_BUF    103731328UL
#define OFF_REC    111731328UL
#define WS_OLD     (OFF_BUF + (size_t)2 * NE * 4)
#define WS_NEW     (OFF_REC + (size_t)2 * NE * 4)

#define NB  391      // bins of 256 nodes: ceil(100000/256)
#define EPB 2048     // edges per block in count/place

// ---------------------------------------------------------------------------
// K0: fused weight W2[k][j] (128 x 256):
//   j<128: ALPHA*W_sd[j][k];  j>=128: (1-ALPHA)*W_ds[j-128][k]
// ---------------------------------------------------------------------------
__global__ __launch_bounds__(256) void build_w2(const float* __restrict__ Wsd,
                                                const float* __restrict__ Wds,
                                                float* __restrict__ W2) {
    int idx = blockIdx.x * 256 + threadIdx.x;
    int k = idx >> 8;
    int j = idx & 255;
    float v;
    if (j < 128) v = ALPHA * Wsd[j * D + k];
    else         v = (1.0f - ALPHA) * Wds[(j - 128) * D + k];
    W2[idx] = v;
}

// ---------------------------------------------------------------------------
// K2: transform GEMM  y[M][256] = x[M][128] @ W2[128][256]   (verified r5)
// ---------------------------------------------------------------------------
__global__ __launch_bounds__(256) void transform(const float* __restrict__ x,
                                                 const float* __restrict__ W2,
                                                 float* __restrict__ y) {
    __shared__ float As[64][132];
    const int tid  = threadIdx.x;
    const int brow = blockIdx.x * 64;
    const int bcol = blockIdx.y * 64;

#pragma unroll
    for (int i = 0; i < 8; ++i) {
        int f   = tid + i * 256;
        int row = f >> 5;
        int kc  = (f & 31) << 2;
        float4 g = make_float4(0.f, 0.f, 0.f, 0.f);
        int grow = brow + row;
        if (grow < NN) g = *(const float4*)&x[(size_t)grow * D + kc];
        *(float4*)&As[row][kc] = g;
    }
    __syncthreads();

    const int ty = tid >> 4;
    const int tx = tid & 15;
    float acc[4][4];
#pragma unroll
    for (int i = 0; i < 4; ++i)
#pragma unroll
        for (int j = 0; j < 4; ++j) acc[i][j] = 0.f;

#pragma unroll 2
    for (int k0 = 0; k0 < 128; k0 += 4) {
        float av[4][4], bv[4][4];
#pragma unroll
        for (int i = 0; i < 4; ++i) {
            float4 t = *(const float4*)&As[ty * 4 + i][k0];
            av[i][0] = t.x; av[i][1] = t.y; av[i][2] = t.z; av[i][3] = t.w;
        }
#pragma unroll
        for (int j = 0; j < 4; ++j) {
            float4 t = *(const float4*)&W2[(size_t)(k0 + j) * 256 + bcol + tx * 4];
            bv[j][0] = t.x; bv[j][1] = t.y; bv[j][2] = t.z; bv[j][3] = t.w;
        }
#pragma unroll
        for (int i = 0; i < 4; ++i)
#pragma unroll
            for (int c = 0; c < 4; ++c)
#pragma unroll
                for (int kk = 0; kk < 4; ++kk)
                    acc[i][c] += av[i][kk] * bv[kk][c];
    }

#pragma unroll
    for (int i = 0; i < 4; ++i) {
        int row = brow + ty * 4 + i;
        if (row < NN) {
            float4 v = make_float4(acc[i][0], acc[i][1], acc[i][2], acc[i][3]);
            *(float4*)&y[(size_t)row * 256 + bcol + tx * 4] = v;
        }
    }
}

// ---------------------------------------------------------------------------
// NEW CSR build: two-level counting sort. Record (4B):
//   rec = (keyLocal<<18) | (partner<<1) | half,  keyLocal = key & 255
// Bucket value for gather = (partner<<8) | (half<<7) = (rec & 0x3FFFF) << 7.
// ---------------------------------------------------------------------------
__global__ __launch_bounds__(512) void zero_bins(int* __restrict__ binCnt) {
    int i = threadIdx.x;
    if (i < NB) binCnt[i] = 0;
}

__global__ __launch_bounds__(256) void count_bins(const int* __restrict__ esrc,
                                                  const int* __restrict__ edst,
                                                  int* __restrict__ binCnt) {
    __shared__ int h[NB];
    int t = threadIdx.x;
    for (int i = t; i < NB; i += 256) h[i] = 0;
    __syncthreads();
    int e0 = blockIdx.x * EPB;
    for (int i = t; i < EPB; i += 256) {
        int e = e0 + i;
        if (e < NE) {
            atomicAdd(&h[edst[e] >> 8], 1);
            atomicAdd(&h[esrc[e] >> 8], 1);
        }
    }
    __syncthreads();
    for (int i = t; i < NB; i += 256)
        if (h[i]) atomicAdd(&binCnt[i], h[i]);
}

__global__ __launch_bounds__(256) void scan_bins(const int* __restrict__ binCnt,
                                                 int* __restrict__ binBase,
                                                 int* __restrict__ binCursor) {
    __shared__ int v[NB];
    int t = threadIdx.x;
    for (int i = t; i < NB; i += 256) v[i] = binCnt[i];
    __syncthreads();
    if (t == 0) {
        int acc = 0;
        for (int i = 0; i < NB; ++i) { int c = v[i]; v[i] = acc; acc += c; }
    }
    __syncthreads();
    for (int i = t; i < NB; i += 256) { binBase[i] = v[i]; binCursor[i] = v[i]; }
}

__global__ __launch_bounds__(256) void place_bins(const int* __restrict__ esrc,
                                                  const int* __restrict__ edst,
                                                  int* __restrict__ binCursor,
                                                  int* __restrict__ rec4) {
    __shared__ int h[NB];
    __shared__ int base[NB];
    __shared__ int lcur[NB];
    int t = threadIdx.x;
    for (int i = t; i < NB; i += 256) h[i] = 0;
    __syncthreads();
    int e0 = blockIdx.x * EPB;
    for (int i = t; i < EPB; i += 256) {
        int e = e0 + i;
        if (e < NE) {
            atomicAdd(&h[edst[e] >> 8], 1);
            atomicAdd(&h[esrc[e] >> 8], 1);
        }
    }
    __syncthreads();
    for (int i = t; i < NB; i += 256) {
        if (h[i]) base[i] = atomicAdd(&binCursor[i], h[i]);
        lcur[i] = 0;
    }
    __syncthreads();
    for (int i = t; i < EPB; i += 256) {
        int e = e0 + i;
        if (e < NE) {
            int s = esrc[e], d = edst[e];
            int bd = d >> 8, bs = s >> 8;
            int p1 = atomicAdd(&lcur[bd], 1);
            rec4[base[bd] + p1] = ((d & 255) << 18) | (s << 1);
            int p2 = atomicAdd(&lcur[bs], 1);
            rec4[base[bs] + p2] = ((s & 255) << 18) | (d << 1) | 1;
        }
    }
}

// One block per bin (256 nodes): per-node hist + scan + ordered placement.
__global__ __launch_bounds__(256) void build_csr(const int* __restrict__ rec4,
                                                 const int* __restrict__ binBase,
                                                 const int* __restrict__ binCnt,
                                                 int* __restrict__ buf,
                                                 int* __restrict__ start,
                                                 int* __restrict__ cnt_out) {
    __shared__ int hc[256];
    __shared__ int st[256];
    int b = blockIdx.x;
    int t = threadIdx.x;
    int node0 = b << 8;
    int r0 = binBase[b];
    int rn = binCnt[b];

    hc[t] = 0;
    __syncthreads();
    for (int i = t; i < rn; i += 256)
        atomicAdd(&hc[rec4[r0 + i] >> 18], 1);
    __syncthreads();
    if (t == 0) {
        int acc = 0;
        for (int i = 0; i < 256; ++i) { st[i] = acc; acc += hc[i]; }
    }
    __syncthreads();
    int n = node0 + t;
    if (n < NN) {
        start[n]   = r0 + st[t];
        cnt_out[n] = hc[t];
    }
    hc[t] = st[t];          // reuse as local cursor
    __syncthreads();
    for (int i = t; i < rn; i += 256) {
        int r = rec4[r0 + i];
        int pos = atomicAdd(&hc[r >> 18], 1);
        buf[r0 + pos] = (r & 0x3FFFF) << 7;   // partner*256 + half*128
    }
}

// ---------------------------------------------------------------------------
// K3: gather (verified r5). One wave per node; lane = dims {2l,2l+1}.
// ---------------------------------------------------------------------------
__global__ __launch_bounds__(256) void gather(const int* __restrict__ start,
                                              const int* __restrict__ cnt,
                                              const int* __restrict__ buf,
                                              const float* __restrict__ y,
                                              const float* __restrict__ bsd,
                                              const float* __restrict__ bds,
                                              float* __restrict__ out) {
    int wave = blockIdx.x * 4 + (threadIdx.x >> 6);
    int lane = threadIdx.x & 63;
    if (wave >= NN) return;
    const int n  = wave;
    const int s0 = start[n];
    const int e0 = s0 + cnt[n];
    const int l2 = lane << 1;

    float a0 = ALPHA * bsd[l2]     + (1.0f - ALPHA) * bds[l2];
    float a1 = ALPHA * bsd[l2 + 1] + (1.0f - ALPHA) * bds[l2 + 1];

    int i = s0;
    for (; i + 4 <= e0; i += 4) {
        int v0 = buf[i], v1 = buf[i + 1], v2 = buf[i + 2], v3 = buf[i + 3];
        float2 p0 = *(const float2*)&y[(size_t)v0 + l2];
        float2 p1 = *(const float2*)&y[(size_t)v1 + l2];
        float2 p2 = *(const float2*)&y[(size_t)v2 + l2];
        float2 p3 = *(const float2*)&y[(size_t)v3 + l2];
        a0 += p0.x + p1.x + p2.x + p3.x;
        a1 += p0.y + p1.y + p2.y + p3.y;
    }
    for (; i < e0; ++i) {
        int v0 = buf[i];
        float2 p0 = *(const float2*)&y[(size_t)v0 + l2];
        a0 += p0.x;
        a1 += p0.y;
    }
    *(float2*)&out[(size_t)n * D + l2] = make_float2(a0, a1);
}

// ---------------------------------------------------------------------------
// OLD CSR build (verified r5) — fallback if ws_size < WS_NEW.
// ---------------------------------------------------------------------------
__global__ __launch_bounds__(256) void zero_cnt(int* __restrict__ cnt,
                                                int* __restrict__ cursor) {
    int i = blockIdx.x * 256 + threadIdx.x;
    if (i < NN) cnt[i] = 0;
    if (i == 0) *cursor = 0;
}

__global__ __launch_bounds__(256) void hist(const int* __restrict__ esrc,
                                            const int* __restrict__ edst,
                                            int* __restrict__ cnt) {
    int e = blockIdx.x * 256 + threadIdx.x;
    if (e < NE) {
        atomicAdd(&cnt[edst[e]], 1);
        atomicAdd(&cnt[esrc[e]], 1);
    }
}

__global__ __launch_bounds__(256) void alloc_ranges(const int* __restrict__ cnt,
                                                    int* __restrict__ start,
                                                    int* __restrict__ cur,
                                                    int* __restrict__ cursor) {
    int n    = blockIdx.x * 256 + threadIdx.x;
    int lane = threadIdx.x & 63;
    int v    = (n < NN) ? cnt[n] : 0;
    int incl = v;
#pragma unroll
    for (int off = 1; off < 64; off <<= 1) {
        int t = __shfl_up(incl, off, 64);
        if (lane >= off) incl += t;
    }
    int total = __shfl(incl, 63, 64);
    int base  = 0;
    if (lane == 63) base = atomicAdd(cursor, total);
    base = __shfl(base, 63, 64);
    if (n < NN) {
        int s = base + incl - v;
        start[n] = s;
        cur[n]   = s;
    }
}

__global__ __launch_bounds__(256) void fill(const int* __restrict__ esrc,
                                            const int* __restrict__ edst,
                                            int* __restrict__ cur,
                                            int* __restrict__ buf) {
    int e = blockIdx.x * 256 + threadIdx.x;
    if (e < NE) {
        int s = esrc[e], d = edst[e];
        int p = atomicAdd(&cur[d], 1);
        buf[p] = s * 256;
        int q = atomicAdd(&cur[s], 1);
        buf[q] = d * 256 + 128;
    }
}

// ---------------------------------------------------------------------------
// Atomic-scatter fallback (verified r2) — if ws_size < WS_OLD.
// ---------------------------------------------------------------------------
__global__ __launch_bounds__(256) void init_out(const float* __restrict__ bsd,
                                                const float* __restrict__ bds,
                                                float* __restrict__ out) {
    int idx = blockIdx.x * 256 + threadIdx.x;
    int d4 = (idx & 31) << 2;
    float4 v;
    v.x = ALPHA * bsd[d4 + 0] + (1.0f - ALPHA) * bds[d4 + 0];
    v.y = ALPHA * bsd[d4 + 1] + (1.0f - ALPHA) * bds[d4 + 1];
    v.z = ALPHA * bsd[d4 + 2] + (1.0f - ALPHA) * bds[d4 + 2];
    v.w = ALPHA * bsd[d4 + 3] + (1.0f - ALPHA) * bds[d4 + 3];
    ((float4*)out)[idx] = v;
}

__global__ __launch_bounds__(256) void scatter(const int* __restrict__ esrc,
                                               const int* __restrict__ edst,
                                               const float* __restrict__ y,
                                               float* __restrict__ out) {
    const int lane = threadIdx.x & 63;
    const int wave = blockIdx.x * 4 + (threadIdx.x >> 6);
    const int nw   = gridDim.x * 4;
    const int l2   = lane << 1;
    for (int e = wave; e < NE; e += nw) {
        int s = esrc[e];
        int d = edst[e];
        float2 a = *(const float2*)&y[(size_t)s * 256 + l2];
        float2 b = *(const float2*)&y[(size_t)d * 256 + 128 + l2];
        float* od = &out[(size_t)d * D + l2];
        float* os = &out[(size_t)s * D + l2];
        unsafeAtomicAdd(od + 0, a.x);
        unsafeAtomicAdd(od + 1, a.y);
        unsafeAtomicAdd(os + 0, b.x);
        unsafeAtomicAdd(os + 1, b.y);
    }
}

// ---------------------------------------------------------------------------
extern "C" void kernel_launch(void* const* d_in, const int* in_sizes, int n_in,
                              void* d_out, int out_size, void* d_ws, size_t ws_size,
                              hipStream_t stream) {
    const float* x    = (const float*)d_in[0];
    const int*   esrc = (const int*)  d_in[1];
    const int*   edst = (const int*)  d_in[2];
    const float* Wsd  = (const float*)d_in[3];
    const float* bsd  = (const float*)d_in[4];
    const float* Wds  = (const float*)d_in[5];
    const float* bds  = (const float*)d_in[6];
    float* out = (float*)d_out;

    char* ws = (char*)d_ws;
    float* y  = (float*)ws;
    float* W2 = (float*)(ws + OFF_W2);

    build_w2<<<128, 256, 0, stream>>>(Wsd, Wds, W2);
    transform<<<dim3((NN + 63) / 64, 4), 256, 0, stream>>>(x, W2, y);

    int* cnt    = (int*)(ws + OFF_CNT);
    int* start  = (int*)(ws + OFF_START);
    int* buf    = (int*)(ws + OFF_BUF);

    if (ws_size >= WS_NEW) {
        // bin arrays live in the (otherwise unused) old cur region
        int* binCnt    = (int*)(ws + OFF_CUR);
        int* binBase   = (int*)(ws + OFF_CUR + 4096);
        int* binCursor = (int*)(ws + OFF_CUR + 8192);
        int* rec4      = (int*)(ws + OFF_REC);
        const int nblk = (NE + EPB - 1) / EPB;   // 489
        zero_bins<<<1, 512, 0, stream>>>(binCnt);
        count_bins<<<nblk, 256, 0, stream>>>(esrc, edst, binCnt);
        scan_bins<<<1, 256, 0, stream>>>(binCnt, binBase, binCursor);
        place_bins<<<nblk, 256, 0, stream>>>(esrc, edst, binCursor, rec4);
        build_csr<<<NB, 256, 0, stream>>>(rec4, binBase, binCnt, buf, start, cnt);
        gather<<<(NN + 3) / 4, 256, 0, stream>>>(start, cnt, buf, y, bsd, bds, out);
    } else if (ws_size >= WS_OLD) {
        int* cur    = (int*)(ws + OFF_CUR);
        int* cursor = (int*)(ws + OFF_CURSOR);
        zero_cnt<<<(NN + 255) / 256, 256, 0, stream>>>(cnt, cursor);
        hist<<<(NE + 255) / 256, 256, 0, stream>>>(esrc, edst, cnt);
        alloc_ranges<<<(NN + 255) / 256, 256, 0, stream>>>(cnt, start, cur, cursor);
        fill<<<(NE + 255) / 256, 256, 0, stream>>>(esrc, edst, cur, buf);
        gather<<<(NN + 3) / 4, 256, 0, stream>>>(start, cnt, buf, y, bsd, bds, out);
    } else {
        init_out<<<(NN * D / 4) / 256, 256, 0, stream>>>(bsd, bds, out);
        scatter<<<2048, 256, 0, stream>>>(esrc, edst, y, out);
    }
}